// Round 1
// baseline (248.677 us; speedup 1.0000x reference)
//
#include <hip/hip_runtime.h>
#include <math.h>

// BlockDiagAttention: B=4,H=16,N=4128,D=64 fp32.
// One 256-thread workgroup per 64x64 diagonal block (65th block = 32-row
// remainder). LDS stride 65 -> bank=(row+k)%32, all access patterns <=2-way.
#define STR 65

__global__ __launch_bounds__(256, 3) void bda_kernel(
    const float* __restrict__ qg,
    const float* __restrict__ kg,
    const float* __restrict__ vg,
    float* __restrict__ og,
    int N, int nblk, int rem) {
  __shared__ float Qs[64 * STR];  // Q tile; reused for S/P after QK^T
  __shared__ float Ks[64 * STR];
  __shared__ float Vs[64 * STR];

  const int wg  = blockIdx.x;
  const int blk = wg % nblk;
  const int bh  = wg / nblk;
  const int nrows = (blk == nblk - 1 && rem != 0) ? rem : 64;
  const size_t base = ((size_t)bh * (size_t)N + (size_t)blk * 64) * 64;

  const int t = threadIdx.x;

  // ---- stage Q,K,V (each block is a contiguous 64x64 f32 = 16KB chunk) ----
#pragma unroll
  for (int i = 0; i < 4; ++i) {
    const int e   = (t << 2) + (i << 10);
    const int row = e >> 6;
    const int col = e & 63;
    float4 qv = make_float4(0.f, 0.f, 0.f, 0.f);
    float4 kv = qv, vv = qv;
    if (row < nrows) {  // zero-fill missing rows of the remainder block
      qv = *(const float4*)(qg + base + e);
      kv = *(const float4*)(kg + base + e);
      vv = *(const float4*)(vg + base + e);
    }
    const int a = row * STR + col;
    Qs[a + 0] = qv.x; Qs[a + 1] = qv.y; Qs[a + 2] = qv.z; Qs[a + 3] = qv.w;
    Ks[a + 0] = kv.x; Ks[a + 1] = kv.y; Ks[a + 2] = kv.z; Ks[a + 3] = kv.w;
    Vs[a + 0] = vv.x; Vs[a + 1] = vv.y; Vs[a + 2] = vv.z; Vs[a + 3] = vv.w;
  }
  __syncthreads();

  const int tx = t & 15;
  const int ty = t >> 4;
  const int r0 = ty << 2;   // 4 output rows
  const int c0 = tx << 2;   // 4 output cols

  // ---- S = (Q K^T)/8, 4x4 register tile per thread ----
  float acc[4][4] = {{0.f}};
  {
    const float* q0 = &Qs[(r0 + 0) * STR];
    const float* q1 = &Qs[(r0 + 1) * STR];
    const float* q2 = &Qs[(r0 + 2) * STR];
    const float* q3 = &Qs[(r0 + 3) * STR];
    const float* k0 = &Ks[(c0 + 0) * STR];
    const float* k1 = &Ks[(c0 + 1) * STR];
    const float* k2 = &Ks[(c0 + 2) * STR];
    const float* k3 = &Ks[(c0 + 3) * STR];
#pragma unroll 4
    for (int kk = 0; kk < 64; ++kk) {
      const float a0 = q0[kk], a1 = q1[kk], a2 = q2[kk], a3 = q3[kk];
      const float b0 = k0[kk], b1 = k1[kk], b2 = k2[kk], b3 = k3[kk];
      acc[0][0] += a0 * b0; acc[0][1] += a0 * b1; acc[0][2] += a0 * b2; acc[0][3] += a0 * b3;
      acc[1][0] += a1 * b0; acc[1][1] += a1 * b1; acc[1][2] += a1 * b2; acc[1][3] += a1 * b3;
      acc[2][0] += a2 * b0; acc[2][1] += a2 * b1; acc[2][2] += a2 * b2; acc[2][3] += a2 * b3;
      acc[3][0] += a3 * b0; acc[3][1] += a3 * b1; acc[3][2] += a3 * b2; acc[3][3] += a3 * b3;
    }
  }
  __syncthreads();  // Q tile dead; reuse Qs for scores
#pragma unroll
  for (int i = 0; i < 4; ++i)
#pragma unroll
    for (int j = 0; j < 4; ++j)
      Qs[(r0 + i) * STR + c0 + j] = acc[i][j] * 0.125f;
  __syncthreads();

  // ---- softmax: row r = t>>2, 4 lanes per row each own 16 cols ----
  {
    const int r = t >> 2;
    const int p = t & 3;
    float s[16];
    float m = -INFINITY;
#pragma unroll
    for (int c = 0; c < 16; ++c) {
      const int col = (p << 4) + c;
      const float x = Qs[r * STR + col];
      s[c] = x;
      m = (col < nrows) ? fmaxf(m, x) : m;
    }
    m = fmaxf(m, __shfl_xor(m, 1));
    m = fmaxf(m, __shfl_xor(m, 2));
    float l = 0.f;
#pragma unroll
    for (int c = 0; c < 16; ++c) {
      const int col = (p << 4) + c;
      const float pv = (col < nrows) ? __expf(s[c] - m) : 0.f;
      s[c] = pv;
      l += pv;
    }
    l += __shfl_xor(l, 1);
    l += __shfl_xor(l, 2);
    const float inv = 1.f / l;  // rows>=nrows: NaN, but those rows are never written
#pragma unroll
    for (int c = 0; c < 16; ++c)
      Qs[r * STR + (p << 4) + c] = s[c] * inv;
  }
  __syncthreads();

  // ---- O = P V, 4x4 register tile per thread ----
  float o[4][4] = {{0.f}};
  {
    const float* p0 = &Qs[(r0 + 0) * STR];
    const float* p1 = &Qs[(r0 + 1) * STR];
    const float* p2 = &Qs[(r0 + 2) * STR];
    const float* p3 = &Qs[(r0 + 3) * STR];
#pragma unroll 4
    for (int j = 0; j < 64; ++j) {
      const float a0 = p0[j], a1 = p1[j], a2 = p2[j], a3 = p3[j];
      const float* vr = &Vs[j * STR + c0];
      const float b0 = vr[0], b1 = vr[1], b2 = vr[2], b3 = vr[3];
      o[0][0] += a0 * b0; o[0][1] += a0 * b1; o[0][2] += a0 * b2; o[0][3] += a0 * b3;
      o[1][0] += a1 * b0; o[1][1] += a1 * b1; o[1][2] += a1 * b2; o[1][3] += a1 * b3;
      o[2][0] += a2 * b0; o[2][1] += a2 * b1; o[2][2] += a2 * b2; o[2][3] += a2 * b3;
      o[3][0] += a3 * b0; o[3][1] += a3 * b1; o[3][2] += a3 * b2; o[3][3] += a3 * b3;
    }
  }
#pragma unroll
  for (int i = 0; i < 4; ++i) {
    const int row = r0 + i;
    if (row < nrows) {
      *(float4*)(og + base + row * 64 + c0) =
          make_float4(o[i][0], o[i][1], o[i][2], o[i][3]);
    }
  }
}

extern "C" void kernel_launch(void* const* d_in, const int* in_sizes, int n_in,
                              void* d_out, int out_size, void* d_ws, size_t ws_size,
                              hipStream_t stream) {
  const float* q = (const float*)d_in[0];
  const float* k = (const float*)d_in[1];
  const float* v = (const float*)d_in[2];
  float* o = (float*)d_out;

  const int N    = 4128;                  // per reference setup_inputs
  const int BH   = in_sizes[0] / (N * 64);  // B*H = 64
  const int nblk = (N + 63) / 64;         // 65 (64 full + 1 remainder)
  const int rem  = N & 63;                // 32

  bda_kernel<<<dim3(BH * nblk), dim3(256), 0, stream>>>(q, k, v, o, N, nblk, rem);
}

// Round 3
// 219.440 us; speedup vs baseline: 1.1332x; 1.1332x over previous
//
#include <hip/hip_runtime.h>
#include <math.h>

// BlockDiagAttention via split-bf16 MFMA (hi+lo, 3-term products ~= fp32).
// One 256-thread WG (4 waves) per 64x64 diagonal block; wave w owns rows
// 16w..16w+15 so softmax is wave-local. LDS row stride 72 bf16 (144B) keeps
// b128 fragment reads uniformly spread over banks.
#define STRH 72

typedef __attribute__((ext_vector_type(8))) short short8;
typedef __attribute__((ext_vector_type(4))) float f32x4;
typedef __attribute__((ext_vector_type(4))) short short4v;

// round-to-nearest-even fp32 -> bf16 hi, plus bf16 of the residual (lo)
__device__ __forceinline__ void split2(float x, unsigned short& h, unsigned short& l) {
  unsigned u = __float_as_uint(x);
  unsigned hb = (u + 0x7FFFu + ((u >> 16) & 1u)) & 0xFFFF0000u;
  h = (unsigned short)(hb >> 16);
  float r = x - __uint_as_float(hb);
  unsigned v = __float_as_uint(r);
  l = (unsigned short)((v + 0x7FFFu + ((v >> 16) & 1u)) >> 16);
}

__global__ __launch_bounds__(256, 4) void bda_kernel(
    const float* __restrict__ qg,
    const float* __restrict__ kg,
    const float* __restrict__ vg,
    float* __restrict__ og,
    int N, int nblk, int rem) {
  __shared__ unsigned short Ah[64 * STRH];  // Q hi  -> later P hi
  __shared__ unsigned short Al[64 * STRH];  // Q lo  -> later P lo
  __shared__ unsigned short Bh[64 * STRH];  // K hi  -> later Vt hi
  __shared__ unsigned short Bl[64 * STRH];  // K lo  -> later Vt lo

  const int wg  = blockIdx.x;
  const int blk = wg % nblk;
  const int bh  = wg / nblk;
  const int nrows = (blk == nblk - 1 && rem != 0) ? rem : 64;
  const size_t base = ((size_t)bh * (size_t)N + (size_t)blk * 64) * 64;

  const int t    = threadIdx.x;
  const int lane = t & 63;
  const int w    = t >> 6;

  // ---- stage Q,K: fp32 -> (hi,lo) bf16 pairs ----
#pragma unroll
  for (int rnd = 0; rnd < 4; ++rnd) {
    const int e = (t << 2) + (rnd << 10);
    const int row = e >> 6, col = e & 63;
    float4 qv = make_float4(0.f, 0.f, 0.f, 0.f);
    float4 kv = qv;
    if (row < nrows) {
      qv = *(const float4*)(qg + base + e);
      kv = *(const float4*)(kg + base + e);
    }
    unsigned short qh[4], ql[4], kh[4], kl[4];
    split2(qv.x, qh[0], ql[0]); split2(qv.y, qh[1], ql[1]);
    split2(qv.z, qh[2], ql[2]); split2(qv.w, qh[3], ql[3]);
    split2(kv.x, kh[0], kl[0]); split2(kv.y, kh[1], kl[1]);
    split2(kv.z, kh[2], kl[2]); split2(kv.w, kh[3], kl[3]);
    const int a = row * STRH + col;
    *(short4v*)&Ah[a] = (short4v){(short)qh[0], (short)qh[1], (short)qh[2], (short)qh[3]};
    *(short4v*)&Al[a] = (short4v){(short)ql[0], (short)ql[1], (short)ql[2], (short)ql[3]};
    *(short4v*)&Bh[a] = (short4v){(short)kh[0], (short)kh[1], (short)kh[2], (short)kh[3]};
    *(short4v*)&Bl[a] = (short4v){(short)kl[0], (short)kl[1], (short)kl[2], (short)kl[3]};
  }

  // ---- early V loads (transposed gather; coalesced 256B rows), used post-QK^T
  const int vd  = t & 63;
  const int vkb = (t >> 6) * 16;
  float vr[16];
#pragma unroll
  for (int i = 0; i < 16; ++i) {
    const int k = vkb + i;
    vr[i] = (k < nrows) ? vg[base + (size_t)k * 64 + vd] : 0.f;
  }

  __syncthreads();  // Q,K staged

  // ---- S = Q K^T (3-term split MFMA), wave computes rows 16w..16w+15 ----
  const int colb = lane & 15;
  const int kofs = (lane >> 4) * 8;
  const int arow = 16 * w + colb;  // A-frag row (Q/P)

  f32x4 acc[4];
#pragma unroll
  for (int i = 0; i < 4; ++i) acc[i] = (f32x4){0.f, 0.f, 0.f, 0.f};

#pragma unroll
  for (int ks = 0; ks < 2; ++ks) {
    const int kb = ks * 32 + kofs;
    const short8 ah = *(const short8*)&Ah[arow * STRH + kb];
    const short8 al = *(const short8*)&Al[arow * STRH + kb];
#pragma unroll
    for (int nt = 0; nt < 4; ++nt) {
      const int brow = 16 * nt + colb;
      const short8 bhv = *(const short8*)&Bh[brow * STRH + kb];
      const short8 blv = *(const short8*)&Bl[brow * STRH + kb];
      acc[nt] = __builtin_amdgcn_mfma_f32_16x16x32_bf16(al, bhv, acc[nt], 0, 0, 0);
      acc[nt] = __builtin_amdgcn_mfma_f32_16x16x32_bf16(ah, blv, acc[nt], 0, 0, 0);
      acc[nt] = __builtin_amdgcn_mfma_f32_16x16x32_bf16(ah, bhv, acc[nt], 0, 0, 0);
    }
  }

  // ---- wave-local softmax over each owned row; P -> split bf16 into Ah/Al ----
  const int rquad = (lane >> 4) * 4;
#pragma unroll
  for (int r = 0; r < 4; ++r) {
    const int grow = 16 * w + rquad + r;
    float s[4];
#pragma unroll
    for (int nt = 0; nt < 4; ++nt) {
      const int col = 16 * nt + colb;
      s[nt] = (col < nrows) ? acc[nt][r] * 0.125f : -1e30f;
    }
    float m = fmaxf(fmaxf(s[0], s[1]), fmaxf(s[2], s[3]));
    m = fmaxf(m, __shfl_xor(m, 1));
    m = fmaxf(m, __shfl_xor(m, 2));
    m = fmaxf(m, __shfl_xor(m, 4));
    m = fmaxf(m, __shfl_xor(m, 8));
    float p[4];
    float lsum = 0.f;
#pragma unroll
    for (int nt = 0; nt < 4; ++nt) {
      p[nt] = __expf(s[nt] - m);
      lsum += p[nt];
    }
    lsum += __shfl_xor(lsum, 1);
    lsum += __shfl_xor(lsum, 2);
    lsum += __shfl_xor(lsum, 4);
    lsum += __shfl_xor(lsum, 8);
    const float inv = 1.f / lsum;
#pragma unroll
    for (int nt = 0; nt < 4; ++nt) {
      unsigned short hh, ll;
      split2(p[nt] * inv, hh, ll);
      Ah[grow * STRH + 16 * nt + colb] = hh;  // own rows only: no cross-wave hazard
      Al[grow * STRH + 16 * nt + colb] = ll;
    }
  }

  __syncthreads();  // all waves done reading K frags; K buffers -> Vt

  // ---- stage V transposed: Vt[d][k], split hi/lo ----
#pragma unroll
  for (int c = 0; c < 4; ++c) {
    unsigned short h4[4], l4[4];
#pragma unroll
    for (int i = 0; i < 4; ++i) split2(vr[4 * c + i], h4[i], l4[i]);
    const int a = vd * STRH + vkb + 4 * c;
    *(short4v*)&Bh[a] = (short4v){(short)h4[0], (short)h4[1], (short)h4[2], (short)h4[3]};
    *(short4v*)&Bl[a] = (short4v){(short)l4[0], (short)l4[1], (short)l4[2], (short)l4[3]};
  }
  __syncthreads();  // Vt staged

  // ---- O = P V (3-term split MFMA) ----
  f32x4 oacc[4];
#pragma unroll
  for (int i = 0; i < 4; ++i) oacc[i] = (f32x4){0.f, 0.f, 0.f, 0.f};

#pragma unroll
  for (int ks = 0; ks < 2; ++ks) {
    const int kb = ks * 32 + kofs;
    const short8 ph = *(const short8*)&Ah[arow * STRH + kb];
    const short8 pl = *(const short8*)&Al[arow * STRH + kb];
#pragma unroll
    for (int nt = 0; nt < 4; ++nt) {
      const int vrow = 16 * nt + colb;
      const short8 vh = *(const short8*)&Bh[vrow * STRH + kb];
      const short8 vl = *(const short8*)&Bl[vrow * STRH + kb];
      oacc[nt] = __builtin_amdgcn_mfma_f32_16x16x32_bf16(pl, vh, oacc[nt], 0, 0, 0);
      oacc[nt] = __builtin_amdgcn_mfma_f32_16x16x32_bf16(ph, vl, oacc[nt], 0, 0, 0);
      oacc[nt] = __builtin_amdgcn_mfma_f32_16x16x32_bf16(ph, vh, oacc[nt], 0, 0, 0);
    }
  }

  // ---- store (C/D layout: row=(lane>>4)*4+reg, col=lane&15) ----
#pragma unroll
  for (int nt = 0; nt < 4; ++nt) {
#pragma unroll
    for (int r = 0; r < 4; ++r) {
      const int row = 16 * w + rquad + r;
      if (row < nrows) {
        og[base + (size_t)row * 64 + 16 * nt + colb] = oacc[nt][r];
      }
    }
  }
}

extern "C" void kernel_launch(void* const* d_in, const int* in_sizes, int n_in,
                              void* d_out, int out_size, void* d_ws, size_t ws_size,
                              hipStream_t stream) {
  const float* q = (const float*)d_in[0];
  const float* k = (const float*)d_in[1];
  const float* v = (const float*)d_in[2];
  float* o = (float*)d_out;

  const int N    = 4128;
  const int BH   = in_sizes[0] / (N * 64);  // 64
  const int nblk = (N + 63) / 64;           // 65
  const int rem  = N & 63;                  // 32

  bda_kernel<<<dim3(BH * nblk), dim3(256), 0, stream>>>(q, k, v, o, N, nblk, rem);
}